// Round 1
// baseline (573.124 us; speedup 1.0000x reference)
//
#include <hip/hip_runtime.h>
#include <hip/hip_bf16.h>

typedef __bf16 bf16_t;
typedef __bf16 bf16x8 __attribute__((ext_vector_type(8)));
typedef float  f32x4  __attribute__((ext_vector_type(4)));

static constexpr int M_ = 8192;   // 4 * 2048
static constexpr int N_ = 4096;   // out_f
static constexpr int K_ = 4096;   // in_f
static constexpr int BM = 128, BN = 128, BK = 32;

// async global->LDS, 16B per lane. LDS dest must be wave-uniform base + lane*16.
__device__ __forceinline__ void load_lds16(const bf16_t* g, bf16_t* l) {
  __builtin_amdgcn_global_load_lds(
      (const __attribute__((address_space(1))) void*)g,
      (__attribute__((address_space(3))) void*)l,
      16, 0, 0);
}

// ---- pass 1: x fp32 -> bf16 ----------------------------------------------
__global__ __launch_bounds__(256) void cvt_x_kernel(const float* __restrict__ x,
                                                    bf16_t* __restrict__ xb) {
  const size_t i = ((size_t)blockIdx.x * 256 + threadIdx.x) * 8;
  const float4 f0 = *(const float4*)(x + i);
  const float4 f1 = *(const float4*)(x + i + 4);
  bf16x8 o;
  o[0] = (bf16_t)f0.x; o[1] = (bf16_t)f0.y; o[2] = (bf16_t)f0.z; o[3] = (bf16_t)f0.w;
  o[4] = (bf16_t)f1.x; o[5] = (bf16_t)f1.y; o[6] = (bf16_t)f1.z; o[7] = (bf16_t)f1.w;
  *(bf16x8*)(xb + i) = o;
}

// ---- pass 2: W[o][i] = q[o][i] * scales[o][i/128] -> bf16 ----------------
__global__ __launch_bounds__(256) void dequant_kernel(const int* __restrict__ q,
                                                      const float* __restrict__ s,
                                                      bf16_t* __restrict__ wb) {
  const size_t base = ((size_t)blockIdx.x * 256 + threadIdx.x) * 8;
  const int o  = (int)(base >> 12);      // row (out_f), K_=4096
  const int ii = (int)(base & 4095);     // col within row; 8 elems stay in one group
  const float sc = s[(o << 5) + (ii >> 7)];  // 32 groups per row
  const int4 q0 = *(const int4*)(q + base);
  const int4 q1 = *(const int4*)(q + base + 4);
  bf16x8 w;
  w[0] = (bf16_t)((float)q0.x * sc); w[1] = (bf16_t)((float)q0.y * sc);
  w[2] = (bf16_t)((float)q0.z * sc); w[3] = (bf16_t)((float)q0.w * sc);
  w[4] = (bf16_t)((float)q1.x * sc); w[5] = (bf16_t)((float)q1.y * sc);
  w[6] = (bf16_t)((float)q1.z * sc); w[7] = (bf16_t)((float)q1.w * sc);
  *(bf16x8*)(wb + base) = w;
}

// ---- pass 3: C[m][n] = A[m][:] . B[n][:] + bias[n]  (B^T GEMM) -----------
// 128x128 tile, BK=32, 4 waves each owning 64x64 (4x4 of 16x16x32 MFMA).
__global__ __launch_bounds__(256) void gemm_kernel(const bf16_t* __restrict__ A,
                                                   const bf16_t* __restrict__ B,
                                                   const float* __restrict__ bias,
                                                   float* __restrict__ C) {
  __shared__ __align__(16) bf16_t As[BM * BK];  // [m][k] row-major, 8 KB
  __shared__ __align__(16) bf16_t Bs[BN * BK];  // [n][k] row-major, 8 KB

  const int tid  = threadIdx.x;
  const int lane = tid & 63;
  const int wave = tid >> 6;
  const int bm = blockIdx.y * BM;
  const int bn = blockIdx.x * BN;
  const int wm = (wave & 1) * 64;
  const int wn = (wave >> 1) * 64;
  const int ln = lane & 15;   // MFMA col (n) / A row (m) selector
  const int lq = lane >> 4;   // quad: k-offset selector, C row group

  // staging: chunk c (0..511) = 16B = row c>>2, k8 (c&3)*8. thread t does c=t and c=t+256.
  const int r0 = tid >> 2;
  const int c0 = (tid & 3) * 8;
  const bf16_t* a0 = A + (size_t)(bm + r0) * K_ + c0;
  const bf16_t* a1 = A + (size_t)(bm + r0 + 64) * K_ + c0;
  const bf16_t* b0 = B + (size_t)(bn + r0) * K_ + c0;
  const bf16_t* b1 = B + (size_t)(bn + r0 + 64) * K_ + c0;
  bf16_t* lA0 = As + (size_t)tid * 8;          // lds byte off = tid*16  (wave-uniform + lane*16)
  bf16_t* lA1 = As + (size_t)(tid + 256) * 8;
  bf16_t* lB0 = Bs + (size_t)tid * 8;
  bf16_t* lB1 = Bs + (size_t)(tid + 256) * 8;

  f32x4 acc[4][4] = {};

  for (int kt = 0; kt < K_; kt += BK) {
    load_lds16(a0 + kt, lA0);
    load_lds16(a1 + kt, lA1);
    load_lds16(b0 + kt, lB0);
    load_lds16(b1 + kt, lB1);
    __syncthreads();  // drains vmcnt(0): staged data visible

    bf16x8 af[4], bq[4];
#pragma unroll
    for (int i = 0; i < 4; ++i)
      af[i] = *(const bf16x8*)(As + (wm + i * 16 + ln) * BK + lq * 8);
#pragma unroll
    for (int j = 0; j < 4; ++j)
      bq[j] = *(const bf16x8*)(Bs + (wn + j * 16 + ln) * BK + lq * 8);
#pragma unroll
    for (int i = 0; i < 4; ++i)
#pragma unroll
      for (int j = 0; j < 4; ++j)
        acc[i][j] = __builtin_amdgcn_mfma_f32_16x16x32_bf16(af[i], bq[j], acc[i][j], 0, 0, 0);

    __syncthreads();  // all waves done reading before next overwrite
  }

  // epilogue: C/D layout col=lane&15, row=(lane>>4)*4+reg  [m89/m91 verified]
#pragma unroll
  for (int j = 0; j < 4; ++j) {
    const int col = bn + wn + j * 16 + ln;
    const float bv = bias[col];
#pragma unroll
    for (int i = 0; i < 4; ++i) {
      const int row0 = bm + wm + i * 16 + lq * 4;
      float* cp = C + (size_t)row0 * N_ + col;
#pragma unroll
      for (int r = 0; r < 4; ++r) {
        *cp = acc[i][j][r] + bv;
        cp += N_;
      }
    }
  }
}

extern "C" void kernel_launch(void* const* d_in, const int* in_sizes, int n_in,
                              void* d_out, int out_size, void* d_ws, size_t ws_size,
                              hipStream_t stream) {
  const float* x    = (const float*)d_in[0];  // [4,2048,4096] fp32
  const int*   qw   = (const int*)d_in[1];    // [4096,4096] int32 in [0,16)
  const float* sc   = (const float*)d_in[2];  // [4096,32] fp32
  const float* bias = (const float*)d_in[3];  // [4096] fp32
  float* out = (float*)d_out;                 // [8192,4096] fp32

  bf16_t* xb = (bf16_t*)d_ws;                 // M_*K_ bf16 = 64 MiB
  bf16_t* wb = xb + (size_t)M_ * K_;          // N_*K_ bf16 = 32 MiB  (ws total 96 MiB)

  cvt_x_kernel<<<(int)(((size_t)M_ * K_) / (256 * 8)), 256, 0, stream>>>(x, xb);
  dequant_kernel<<<(int)(((size_t)N_ * K_) / (256 * 8)), 256, 0, stream>>>(qw, sc, wb);

  dim3 grid(N_ / BN, M_ / BM);  // 32 x 64 = 2048 blocks
  gemm_kernel<<<grid, 256, 0, stream>>>(xb, wb, bias, out);
}